// Round 5
// baseline (354.551 us; speedup 1.0000x reference)
//
#include <hip/hip_runtime.h>
#include <math.h>

#define NU_F 0.0031830988618379067f

// Dense 128x128 f16 H tile (32768 B exactly -> 5 blocks/CU) with T2-style
// XOR swizzle replacing the old HS=136 padding: half-index n ^= (m&7)<<3
// (byte bits 4..6). 8-half-aligned b128 accesses stay contiguous; b128 reads
// are bank-balanced (8 dword-accesses per bank per instr = ideal); b16
// column stores stay 2-way (free): rows r and r+4 land on disjoint 16-bank
// halves via the bit-5 XOR.
#define HOFF(m, n) (((m) << 7) + ((n) ^ (((m) & 7) << 3)))

typedef __attribute__((ext_vector_type(8))) _Float16 half8;
typedef __attribute__((ext_vector_type(4))) _Float16 half4;
typedef __attribute__((ext_vector_type(16))) float f32x16;

// tanh via exp2 + fast rcp: ~5 VALU (2 on trans pipe). inf-safe: e=inf -> 1, e=0 -> -1.
__device__ __forceinline__ float fast_tanh(float x) {
    const float e = __builtin_amdgcn_exp2f(x * 2.8853900817779268f);  // e^(2x)
    const float r = __builtin_amdgcn_rcpf(e + 1.f);
    return fmaf(-2.f, r, 1.f);
}

// ---------------------------------------------------------------------------
// Weight prep: W[l][k][n] fp32 -> k-tiled fp16:
//   idx = l*16384 + (k>>4)*2048 + n*16 + (k&15)
// A wave's per-kt B-read (16 halves/lane, n-contiguous) is one 1KB block.
// ---------------------------------------------------------------------------
__global__ void prep_kernel(const float* __restrict__ W1,
                            const float* __restrict__ W2,
                            const float* __restrict__ W3,
                            _Float16* __restrict__ ws)
{
    const int g = blockIdx.x * 256 + threadIdx.x;   // 0..49151
    const int l = g >> 14;
    const int r = g & 16383;
    const int n = r & 127;
    const int k = r >> 7;
    const float* W = (l == 0) ? W1 : (l == 1) ? W2 : W3;
    const float w = W[k * 128 + n];
    ws[l * 16384 + (k >> 4) * 2048 + n * 16 + (k & 15)] = (_Float16)w;
}

// ---------------------------------------------------------------------------
// R3 structure (proven best: M=128, 1x4 N-split, Z-trick, B software-
// pipeline) with LDS trimmed 34.8KB -> 32KB via XOR swizzle -> 5 blocks/CU
// (20 waves, was 16). Per-wave instruction stream otherwise identical.
// Blocks 0..4095: equation, 32 pts (M=128 rows, m = 4p + channel).
// Blocks 4096..4159: init/bound forward-only, 128 pts (m = p).
// Wave w computes cols [32w,32w+32) for all 128 rows (mt=0..3).
// ---------------------------------------------------------------------------
__launch_bounds__(256, 5)
__global__ void pinn_kernel(const float* __restrict__ tx_eq,
                            const float* __restrict__ tx_init,
                            const float* __restrict__ tx_bnd,
                            const float* __restrict__ W0, const float* __restrict__ b0,
                            const float* __restrict__ b1, const float* __restrict__ b2,
                            const float* __restrict__ b3,
                            const float* __restrict__ W4, const float* __restrict__ b4,
                            const _Float16* __restrict__ wt,
                            float* __restrict__ out)
{
    __shared__ _Float16 Hh[128 * 128];   // 32 KB exactly, in-place across layers

    const int tid   = threadIdx.x;
    const int blk   = blockIdx.x;
    const bool is_eq = (blk < 4096);
    const int w     = tid >> 6;
    const int lane  = tid & 63;
    const int col   = lane & 31;
    const int khalf = lane >> 5;
    const int ncol  = 32 * w + col;
    const int wofs  = ncol * 16 + khalf * 8;

    // ---- earliest VMEM: the point coordinates (oldest in queue) ----
    float tv, xv;
    if (is_eq) {
        const float2 t2 = ((const float2*)tx_eq)[blk * 32 + (tid >> 3)];
        tv = t2.x; xv = t2.y;
    } else {
        const int p  = tid >> 1;
        const int gp = (blk - 4096) * 128 + p;
        const float2* src = (gp < 4096) ? (const float2*)tx_init : (const float2*)tx_bnd;
        const int idx = (gp < 4096) ? gp : gp - 4096;
        const float2 t2 = src[idx];
        tv = t2.x; xv = t2.y;
    }

    // ---- layer-0 B prefetch: issued here, consumed after the input barrier ----
    const _Float16* ph = wt + wofs;
    half8 q0 = *(const half8*)(ph);
    half8 q1 = *(const half8*)(ph + 2048);
    half8 q2 = *(const half8*)(ph + 4096);
    half8 q3 = *(const half8*)(ph + 6144);
    half8 q4 = *(const half8*)(ph + 8192);
    half8 q5 = *(const half8*)(ph + 10240);
    half8 q6 = *(const half8*)(ph + 12288);
    half8 q7 = *(const half8*)(ph + 14336);

    // never-written zero C-operand (init once, reused all 3 layers)
    f32x16 Z;
    #pragma unroll
    for (int e = 0; e < 16; ++e) Z[e] = 0.f;

    // ---- input layer (K=2, pointwise, fp32) ----
    if (is_eq) {
        const int p  = tid >> 3;                 // 0..31
        const int f0 = (tid & 7) * 16;
        const int m0 = 4 * p;
        #pragma unroll
        for (int half = 0; half < 2; ++half) {
            const int fb = f0 + 8 * half;
            float vch[4][8];
            #pragma unroll
            for (int j = 0; j < 8; ++j) {
                const int f = fb + j;
                const float w0v = W0[f];             // dz/dt
                const float w1v = W0[128 + f];       // dz/dx
                const float z = fmaf(tv, w0v, fmaf(xv, w1v, b0[f]));
                const float a = fast_tanh(z);
                const float s = 1.f - a * a;
                vch[0][j] = a;
                vch[1][j] = s * w0v;
                vch[2][j] = s * w1v;
                vch[3][j] = -2.f * a * s * w1v * w1v;
            }
            #pragma unroll
            for (int c = 0; c < 4; ++c) {
                half8 hh;
                #pragma unroll
                for (int j = 0; j < 8; ++j) hh[j] = (_Float16)vch[c][j];
                *(half8*)&Hh[HOFF(m0 + c, fb)] = hh;
            }
        }
    } else {
        const int p  = tid >> 1;                 // 0..127 == row m
        const int f0 = (tid & 1) * 64;
        #pragma unroll
        for (int g = 0; g < 8; ++g) {
            half8 hh;
            #pragma unroll
            for (int j = 0; j < 8; ++j) {
                const int f = f0 + 8 * g + j;
                hh[j] = (_Float16)fast_tanh(fmaf(tv, W0[f], fmaf(xv, W0[128 + f], b0[f])));
            }
            *(half8*)&Hh[HOFF(p, f0 + 8 * g)] = hh;
        }
    }
    __syncthreads();

    const float* barr[3] = {b1, b2, b3};

    #pragma unroll 1
    for (int layer = 0; layer < 3; ++layer) {
        const float bias = barr[layer][ncol];

        f32x16 acc0, acc1, acc2, acc3;

#define KSTEP0(Q)                                                             \
        {                                                                     \
            const int k0 = khalf * 8;                                         \
            const half8 ah0 = *(const half8*)&Hh[HOFF(col, k0)];              \
            const half8 ah1 = *(const half8*)&Hh[HOFF(32 + col, k0)];         \
            const half8 ah2 = *(const half8*)&Hh[HOFF(64 + col, k0)];         \
            const half8 ah3 = *(const half8*)&Hh[HOFF(96 + col, k0)];         \
            acc0 = __builtin_amdgcn_mfma_f32_32x32x16_f16(ah0, Q, Z, 0, 0, 0); \
            acc1 = __builtin_amdgcn_mfma_f32_32x32x16_f16(ah1, Q, Z, 0, 0, 0); \
            acc2 = __builtin_amdgcn_mfma_f32_32x32x16_f16(ah2, Q, Z, 0, 0, 0); \
            acc3 = __builtin_amdgcn_mfma_f32_32x32x16_f16(ah3, Q, Z, 0, 0, 0); \
        }
#define KSTEP(KT, Q)                                                          \
        {                                                                     \
            const int k0 = KT * 16 + khalf * 8;                               \
            const half8 ah0 = *(const half8*)&Hh[HOFF(col, k0)];              \
            const half8 ah1 = *(const half8*)&Hh[HOFF(32 + col, k0)];         \
            const half8 ah2 = *(const half8*)&Hh[HOFF(64 + col, k0)];         \
            const half8 ah3 = *(const half8*)&Hh[HOFF(96 + col, k0)];         \
            acc0 = __builtin_amdgcn_mfma_f32_32x32x16_f16(ah0, Q, acc0, 0, 0, 0); \
            acc1 = __builtin_amdgcn_mfma_f32_32x32x16_f16(ah1, Q, acc1, 0, 0, 0); \
            acc2 = __builtin_amdgcn_mfma_f32_32x32x16_f16(ah2, Q, acc2, 0, 0, 0); \
            acc3 = __builtin_amdgcn_mfma_f32_32x32x16_f16(ah3, Q, acc3, 0, 0, 0); \
        }
        KSTEP0(q0) KSTEP(1, q1) KSTEP(2, q2) KSTEP(3, q3)
        KSTEP(4, q4) KSTEP(5, q5) KSTEP(6, q6) KSTEP(7, q7)
#undef KSTEP0
#undef KSTEP

        // ---- next layer's B prefetch: q-regs just consumed, reload now so
        // L2 latency hides under epilogue compute + both barriers.
        if (layer < 2) {
            ph += 16384;
            q0 = *(const half8*)(ph);
            q1 = *(const half8*)(ph + 2048);
            q2 = *(const half8*)(ph + 4096);
            q3 = *(const half8*)(ph + 6144);
            q4 = *(const half8*)(ph + 8192);
            q5 = *(const half8*)(ph + 10240);
            q6 = *(const half8*)(ph + 12288);
            q7 = *(const half8*)(ph + 14336);
        }

        // epilogue COMPUTE (registers only, before the barrier). C-layout:
        // reg group 4g..4g+3 = rows mt*32+8g+4khalf+{0..3} = the 4 derivative
        // channels of one point (eq) -> chain rule in registers.
        half4 h16[4][4];
        #pragma unroll
        for (int mt = 0; mt < 4; ++mt)
            #pragma unroll
            for (int g = 0; g < 4; ++g) {
                const float A0 = (mt == 0 ? acc0 : mt == 1 ? acc1 : mt == 2 ? acc2 : acc3)[4 * g + 0];
                const float A1 = (mt == 0 ? acc0 : mt == 1 ? acc1 : mt == 2 ? acc2 : acc3)[4 * g + 1];
                const float A2 = (mt == 0 ? acc0 : mt == 1 ? acc1 : mt == 2 ? acc2 : acc3)[4 * g + 2];
                const float A3 = (mt == 0 ? acc0 : mt == 1 ? acc1 : mt == 2 ? acc2 : acc3)[4 * g + 3];
                half4 hv;
                if (is_eq) {
                    const float t = fast_tanh(A0 + bias);
                    const float s = 1.f - t * t;
                    hv[0] = (_Float16)t;
                    hv[1] = (_Float16)(s * A1);
                    hv[2] = (_Float16)(s * A2);
                    hv[3] = (_Float16)fmaf(s, A3, -2.f * t * s * A2 * A2);
                } else {
                    hv[0] = (_Float16)fast_tanh(A0 + bias);
                    hv[1] = (_Float16)fast_tanh(A1 + bias);
                    hv[2] = (_Float16)fast_tanh(A2 + bias);
                    hv[3] = (_Float16)fast_tanh(A3 + bias);
                }
                h16[mt][g] = hv;
            }

        __syncthreads();   // all reads of H done -> in-place overwrite safe

        // epilogue STORE (the only work between the two barriers)
        #pragma unroll
        for (int mt = 0; mt < 4; ++mt)
            #pragma unroll
            for (int g = 0; g < 4; ++g) {
                const int mrow0 = mt * 32 + 8 * g + 4 * khalf;
                Hh[HOFF(mrow0 + 0, ncol)] = h16[mt][g][0];
                Hh[HOFF(mrow0 + 1, ncol)] = h16[mt][g][1];
                Hh[HOFF(mrow0 + 2, ncol)] = h16[mt][g][2];
                Hh[HOFF(mrow0 + 3, ncol)] = h16[mt][g][3];
            }
        __syncthreads();
    }

    // ---- final layer (128 -> 1): thread t reduces k-half (t&1) of row t>>1
    {
        const float b4v = b4[0];
        const int m = tid >> 1;
        const int q = tid & 1;
        float dot = 0.f;
        #pragma unroll
        for (int g = 0; g < 8; ++g) {
            const int f = 64 * q + 8 * g;
            const half8 hh = *(const half8*)&Hh[HOFF(m, f)];
            const float4 wa = *(const float4*)&W4[f];
            const float4 wb = *(const float4*)&W4[f + 4];
            dot = fmaf((float)hh[0], wa.x, dot);
            dot = fmaf((float)hh[1], wa.y, dot);
            dot = fmaf((float)hh[2], wa.z, dot);
            dot = fmaf((float)hh[3], wa.w, dot);
            dot = fmaf((float)hh[4], wb.x, dot);
            dot = fmaf((float)hh[5], wb.y, dot);
            dot = fmaf((float)hh[6], wb.z, dot);
            dot = fmaf((float)hh[7], wb.w, dot);
        }
        dot += __shfl_xor(dot, 1);   // full row-dot at both lanes of the pair

        if (is_eq) {
            // wave w holds rows [32w,32w+32) = points [8w,8w+8);
            // row r of point pl (=4pl+c) sits at lanes 8pl+2c (+q).
            const int base = (lane & 7) * 8;
            const float uu   = __shfl(dot, base + 0) + b4v;
            const float utv  = __shfl(dot, base + 2);
            const float uxv  = __shfl(dot, base + 4);
            const float uxxv = __shfl(dot, base + 6);
            if (lane < 8)
                out[blk * 32 + 8 * w + lane] = fmaf(uu, uxv, utv) - NU_F * uxxv;
        } else {
            if (q == 0)
                out[131072 + (blk - 4096) * 128 + m] = dot + b4v;
        }
    }
}

extern "C" void kernel_launch(void* const* d_in, const int* in_sizes, int n_in,
                              void* d_out, int out_size, void* d_ws, size_t ws_size,
                              hipStream_t stream)
{
    const float* tx_eq   = (const float*)d_in[0];
    const float* tx_init = (const float*)d_in[1];
    const float* tx_bnd  = (const float*)d_in[2];
    const float* W0 = (const float*)d_in[3];
    const float* b0 = (const float*)d_in[4];
    const float* W1 = (const float*)d_in[5];
    const float* b1 = (const float*)d_in[6];
    const float* W2 = (const float*)d_in[7];
    const float* b2 = (const float*)d_in[8];
    const float* W3 = (const float*)d_in[9];
    const float* b3 = (const float*)d_in[10];
    const float* W4 = (const float*)d_in[11];
    const float* b4 = (const float*)d_in[12];
    float* out = (float*)d_out;
    _Float16* wt = (_Float16*)d_ws;   // needs 98304 B

    hipLaunchKernelGGL(prep_kernel, dim3(192), dim3(256), 0, stream, W1, W2, W3, wt);
    // 4096 eq blocks (32 pts) + 64 ib blocks (128 pts)
    hipLaunchKernelGGL(pinn_kernel, dim3(4160), dim3(256), 0, stream,
                       tx_eq, tx_init, tx_bnd, W0, b0, b1, b2, b3, W4, b4,
                       (const _Float16*)wt, out);
}

// Round 6
// 272.624 us; speedup vs baseline: 1.3005x; 1.3005x over previous
//
#include <hip/hip_runtime.h>
#include <math.h>

#define NU_F 0.0031830988618379067f

typedef __attribute__((ext_vector_type(8))) _Float16 half8;
typedef __attribute__((ext_vector_type(16))) float f32x16;

// tanh via exp2 + fast rcp: ~5 VALU (2 on trans pipe). inf-safe: e=inf -> 1, e=0 -> -1.
__device__ __forceinline__ float fast_tanh(float x) {
    const float e = __builtin_amdgcn_exp2f(x * 2.8853900817779268f);  // e^(2x)
    const float r = __builtin_amdgcn_rcpf(e + 1.f);
    return fmaf(-2.f, r, 1.f);
}

// pack two f32 -> one b32 of two f16 (RNE via scalar casts)
__device__ __forceinline__ uint32_t pack2(float x, float y) {
    union { _Float16 h[2]; uint32_t u; } r;
    r.h[0] = (_Float16)x; r.h[1] = (_Float16)y;
    return r.u;
}

__device__ __forceinline__ half8 pack8(const float* v) {
    union { uint32_t u[4]; half8 h; } r;
    r.u[0] = pack2(v[0], v[1]);
    r.u[1] = pack2(v[2], v[3]);
    r.u[2] = pack2(v[4], v[5]);
    r.u[3] = pack2(v[6], v[7]);
    return r.h;
}

// quad broadcast via DPP quad_perm (lane quads = the 4 derivative channels)
template<int CTRL>
__device__ __forceinline__ float qb(float v) {
    union { float f; int i; } a, b;
    a.f = v;
    b.i = __builtin_amdgcn_update_dpp(0, a.i, CTRL, 0xF, 0xF, true);
    return b.f;
}

// ---------------------------------------------------------------------------
// Weight prep for the operand-role-swapped kernel. The W-fragment is the
// MFMA *A* operand (lane = output col n, k-slots in regs); the k-order is the
// permutation pi(kt,h,j) = 32*(kt>>1) + 16*(kt&1) + 4h + (j&3) + 8*(j>>2)
// that matches the register order in which the previous layer's D-output
// (lane = row m, n's in regs) is packed into the B operand.
// ws layout: halves, chunk ((l*8+kt)*4+tn)*512 + lane*8 + j. 96 KB total.
// ---------------------------------------------------------------------------
__global__ void prep_kernel(const float* __restrict__ W1,
                            const float* __restrict__ W2,
                            const float* __restrict__ W3,
                            _Float16* __restrict__ ws)
{
    const int g = blockIdx.x * 256 + threadIdx.x;   // 0..49151
    const int j    = g & 7;
    const int lane = (g >> 3) & 63;
    const int tn   = (g >> 9) & 3;
    const int kt   = (g >> 11) & 7;
    const int l    = g >> 14;                       // 0..2
    const int h    = lane >> 5;
    const int n    = 32 * tn + (lane & 31);
    const int k    = 32 * (kt >> 1) + 16 * (kt & 1) + 4 * h + (j & 3) + 8 * (j >> 2);
    const float* W = (l == 0) ? W1 : (l == 1) ? W2 : W3;
    ws[g] = (_Float16)W[k * 128 + n];
}

// ---------------------------------------------------------------------------
// Fully register-resident PINN: zero LDS, zero barriers.
// Wave w owns rows [32w, 32w+32): lane (l&31) = local row m; lanes l and l+32
// hold complementary feature-halves (h = l>>5) of the SAME row.
// Hidden layer: D = A(W-frag) * B(H-frag): D lane = m, 16 n's per acc-reg at
// n(t,r,h) = 32t + (r&3) + 8*(r>>2) + 4h. Pack D directly into the next
// layer's B-frags (k-order matched by prep's pi). Chain rule for eq blocks is
// cross-lane within a point-quad (lanes 4p..4p+3 = channels 0..3) via 2 DPP
// quad-broadcasts per value. Bias/W0/W4 gathers are 4-contiguous in the
// permuted order -> direct float4 loads from the original arrays.
// Blocks 0..4095: eq, 32 pts. Blocks 4096..4159: init/bound, 128 pts.
// ---------------------------------------------------------------------------
__launch_bounds__(256, 3)
__global__ void pinn_kernel(const float* __restrict__ tx_eq,
                            const float* __restrict__ tx_init,
                            const float* __restrict__ tx_bnd,
                            const float* __restrict__ W0, const float* __restrict__ b0,
                            const float* __restrict__ b1, const float* __restrict__ b2,
                            const float* __restrict__ b3,
                            const float* __restrict__ W4, const float* __restrict__ b4,
                            const _Float16* __restrict__ wt,
                            float* __restrict__ out)
{
    const int tid = threadIdx.x;
    const int blk = blockIdx.x;
    const bool is_eq = (blk < 4096);
    const int w    = tid >> 6;
    const int lane = tid & 63;
    const int lr   = lane & 31;     // local row m within the wave's 32-row tile
    const int h    = lane >> 5;     // feature-half
    const int c    = lr & 3;        // eq derivative channel (quad-local)
    const int h4   = 4 * h;

    // ---- point coordinates ----
    float tv, xv;
    if (is_eq) {
        const float2 t2 = ((const float2*)tx_eq)[blk * 32 + 8 * w + (lr >> 2)];
        tv = t2.x; xv = t2.y;
    } else {
        const int gp = (blk - 4096) * 128 + 32 * w + lr;
        const float2* src = (gp < 4096) ? (const float2*)tx_init : (const float2*)tx_bnd;
        const float2 t2 = src[(gp < 4096) ? gp : gp - 4096];
        tv = t2.x; xv = t2.y;
    }
    const float bm = (is_eq && c != 0) ? 0.f : 1.f;   // bias mask (tangent rows: 0)

    // ---- input layer: compute H1[m][n(t,r,h)] straight into B-frags ----
    half8 ph[8];
    #pragma unroll
    for (int t = 0; t < 4; ++t) {
        float v16[16];
        #pragma unroll
        for (int q = 0; q < 4; ++q) {
            const int f0 = 32 * t + 8 * q + h4;
            const float4 w0c = *(const float4*)&W0[f0];
            const float4 w1c = *(const float4*)&W0[128 + f0];
            const float4 b0c = *(const float4*)&b0[f0];
            #pragma unroll
            for (int e = 0; e < 4; ++e) {
                const float w0v = (e == 0) ? w0c.x : (e == 1) ? w0c.y : (e == 2) ? w0c.z : w0c.w;
                const float w1v = (e == 0) ? w1c.x : (e == 1) ? w1c.y : (e == 2) ? w1c.z : w1c.w;
                const float b0v = (e == 0) ? b0c.x : (e == 1) ? b0c.y : (e == 2) ? b0c.z : b0c.w;
                const float z = fmaf(tv, w0v, fmaf(xv, w1v, b0v));
                const float a = fast_tanh(z);
                float o = a;
                if (is_eq) {
                    const float s = 1.f - a * a;
                    const float v1 = s * w0v;
                    const float v2 = s * w1v;
                    const float v3 = -2.f * a * s * w1v * w1v;
                    o = (c == 0) ? a : (c == 1) ? v1 : (c == 2) ? v2 : v3;
                }
                v16[4 * q + e] = o;
            }
        }
        ph[2 * t]     = pack8(&v16[0]);
        ph[2 * t + 1] = pack8(&v16[8]);
    }

    // ---- 3 hidden layers, all in registers ----
    const float* barr[3] = {b1, b2, b3};
    const _Float16* pw = wt;
    float dot = 0.f;

    #pragma unroll 1
    for (int l = 0; l < 3; ++l) {
        const float* __restrict__ bl = barr[l];

        // C-init = bias (channel-0 / ib rows only)
        f32x16 acc[4];
        #pragma unroll
        for (int t = 0; t < 4; ++t)
            #pragma unroll
            for (int q = 0; q < 4; ++q) {
                const float4 bc = *(const float4*)&bl[32 * t + 8 * q + h4];
                acc[t][4 * q + 0] = bc.x * bm;
                acc[t][4 * q + 1] = bc.y * bm;
                acc[t][4 * q + 2] = bc.z * bm;
                acc[t][4 * q + 3] = bc.w * bm;
            }

        // 32 MFMAs: A = W-frag (streamed), B = ph[kt] (register-resident H)
        #pragma unroll
        for (int kt = 0; kt < 8; ++kt) {
            const _Float16* pb = pw + kt * 2048 + lane * 8;
            const half8 wf0 = *(const half8*)(pb);
            const half8 wf1 = *(const half8*)(pb + 512);
            const half8 wf2 = *(const half8*)(pb + 1024);
            const half8 wf3 = *(const half8*)(pb + 1536);
            acc[0] = __builtin_amdgcn_mfma_f32_32x32x16_f16(wf0, ph[kt], acc[0], 0, 0, 0);
            acc[1] = __builtin_amdgcn_mfma_f32_32x32x16_f16(wf1, ph[kt], acc[1], 0, 0, 0);
            acc[2] = __builtin_amdgcn_mfma_f32_32x32x16_f16(wf2, ph[kt], acc[2], 0, 0, 0);
            acc[3] = __builtin_amdgcn_mfma_f32_32x32x16_f16(wf3, ph[kt], acc[3], 0, 0, 0);
        }
        pw += 16384;

        // epilogue: activation (+ chain rule via quad DPP for eq);
        // last layer folds the 128->1 dot instead of repacking.
        const bool last = (l == 2);
        #pragma unroll
        for (int t = 0; t < 4; ++t) {
            float v16[16];
            #pragma unroll
            for (int r = 0; r < 16; ++r) {
                const float z = acc[t][r];
                float o;
                if (is_eq) {
                    const float z0 = qb<0x00>(z);          // A0 + bias (lane c=0)
                    const float z2 = qb<0xAA>(z);          // raw A2   (lane c=2)
                    const float tt = fast_tanh(z0);
                    const float s  = 1.f - tt * tt;
                    const float v12 = s * z;
                    const float m3  = tt * s * z2;
                    const float v3  = fmaf(s, z, -2.f * m3 * z2);
                    o = (c == 0) ? tt : (c == 3) ? v3 : v12;
                } else {
                    o = fast_tanh(z);
                }
                v16[r] = o;
            }
            if (last) {
                #pragma unroll
                for (int q = 0; q < 4; ++q) {
                    const float4 w4c = *(const float4*)&W4[32 * t + 8 * q + h4];
                    dot = fmaf(v16[4 * q + 0], w4c.x, dot);
                    dot = fmaf(v16[4 * q + 1], w4c.y, dot);
                    dot = fmaf(v16[4 * q + 2], w4c.z, dot);
                    dot = fmaf(v16[4 * q + 3], w4c.w, dot);
                }
            } else {
                ph[2 * t]     = pack8(&v16[0]);
                ph[2 * t + 1] = pack8(&v16[8]);
            }
        }
    }

    // ---- final combine: lanes l / l+32 hold complementary feature halves ----
    dot += __shfl_xor(dot, 32);
    const float b4v = b4[0];
    if (is_eq) {
        const float u   = qb<0x00>(dot) + b4v;   // channel lanes: 0=u 1=ut 2=ux 3=uxx
        const float ut  = qb<0x55>(dot);
        const float ux  = qb<0xAA>(dot);
        const float uxx = qb<0xFF>(dot);
        if (lane < 32 && c == 0)
            out[blk * 32 + 8 * w + (lr >> 2)] = fmaf(u, ux, ut) - NU_F * uxx;
    } else {
        if (lane < 32)
            out[131072 + (blk - 4096) * 128 + 32 * w + lr] = dot + b4v;
    }
}

extern "C" void kernel_launch(void* const* d_in, const int* in_sizes, int n_in,
                              void* d_out, int out_size, void* d_ws, size_t ws_size,
                              hipStream_t stream)
{
    const float* tx_eq   = (const float*)d_in[0];
    const float* tx_init = (const float*)d_in[1];
    const float* tx_bnd  = (const float*)d_in[2];
    const float* W0 = (const float*)d_in[3];
    const float* b0 = (const float*)d_in[4];
    const float* W1 = (const float*)d_in[5];
    const float* b1 = (const float*)d_in[6];
    const float* W2 = (const float*)d_in[7];
    const float* b2 = (const float*)d_in[8];
    const float* W3 = (const float*)d_in[9];
    const float* b3 = (const float*)d_in[10];
    const float* W4 = (const float*)d_in[11];
    const float* b4 = (const float*)d_in[12];
    float* out = (float*)d_out;
    _Float16* wt = (_Float16*)d_ws;   // needs 98304 B (uses 96 KB)

    hipLaunchKernelGGL(prep_kernel, dim3(192), dim3(256), 0, stream, W1, W2, W3, wt);
    // 4096 eq blocks (32 pts) + 64 ib blocks (128 pts)
    hipLaunchKernelGGL(pinn_kernel, dim3(4160), dim3(256), 0, stream,
                       tx_eq, tx_init, tx_bnd, W0, b0, b1, b2, b3, W4, b4,
                       (const _Float16*)wt, out);
}

// Round 7
// 164.341 us; speedup vs baseline: 2.1574x; 1.6589x over previous
//
#include <hip/hip_runtime.h>
#include <math.h>

#define NU_F 0.0031830988618379067f
#define HS 136   // halves per H row: 17*8 -> 16B-aligned, odd 16B-stride = bank-balanced

typedef __attribute__((ext_vector_type(8))) _Float16 half8;
typedef __attribute__((ext_vector_type(4))) _Float16 half4;
typedef __attribute__((ext_vector_type(16))) float f32x16;

// tanh via exp2 + fast rcp: ~5 VALU (2 on trans pipe). inf-safe: e=inf -> 1, e=0 -> -1.
__device__ __forceinline__ float fast_tanh(float x) {
    const float e = __builtin_amdgcn_exp2f(x * 2.8853900817779268f);  // e^(2x)
    const float r = __builtin_amdgcn_rcpf(e + 1.f);
    return fmaf(-2.f, r, 1.f);
}

// lane^1 exchange via DPP quad_perm [1,0,3,2]
__device__ __forceinline__ uint32_t dpp_x1(uint32_t v) {
    return (uint32_t)__builtin_amdgcn_update_dpp(0, (int)v, 0xB1, 0xF, 0xF, true);
}

// ---------------------------------------------------------------------------
// Weight prep: W[l][k][n] fp32 -> k-tiled fp16:
//   idx = l*16384 + (k>>4)*2048 + n*16 + (k&15)
// A wave's per-kt B-read (16 halves/lane, n-contiguous) is one 1KB block.
// ---------------------------------------------------------------------------
__global__ void prep_kernel(const float* __restrict__ W1,
                            const float* __restrict__ W2,
                            const float* __restrict__ W3,
                            _Float16* __restrict__ ws)
{
    const int g = blockIdx.x * 256 + threadIdx.x;   // 0..49151
    const int l = g >> 14;
    const int r = g & 16383;
    const int n = r & 127;
    const int k = r >> 7;
    const float* W = (l == 0) ? W1 : (l == 1) ? W2 : W3;
    const float w = W[k * 128 + n];
    ws[l * 16384 + (k >> 4) * 2048 + n * 16 + (k & 15)] = (_Float16)w;
}

// ---------------------------------------------------------------------------
// R3 structure (proven best: M=128, 1x4 N-split, Z-trick, B software-
// pipeline, 4 blk/CU) + paired b32 epilogue stores: lane pair (even,odd col)
// exchanges via 1 DPP + 2 v_perm in the PRE-barrier compute phase, so the
// between-barriers store phase is 32 ds_write_b32 instead of 64 ds_write_b16
// (the only un-overlappable phase in the block -> direct critical-path cut).
// Blocks 0..4095: equation, 32 pts (M=128 rows, m = 4p + channel).
// Blocks 4096..4159: init/bound forward-only, 128 pts (m = p).
// Wave w computes cols [32w,32w+32) for all 128 rows (mt=0..3).
// ---------------------------------------------------------------------------
__launch_bounds__(256, 4)
__global__ void pinn_kernel(const float* __restrict__ tx_eq,
                            const float* __restrict__ tx_init,
                            const float* __restrict__ tx_bnd,
                            const float* __restrict__ W0, const float* __restrict__ b0,
                            const float* __restrict__ b1, const float* __restrict__ b2,
                            const float* __restrict__ b3,
                            const float* __restrict__ W4, const float* __restrict__ b4,
                            const _Float16* __restrict__ wt,
                            float* __restrict__ out)
{
    __shared__ _Float16 Hh[128][HS];   // 34.8 KB, in-place across layers

    const int tid   = threadIdx.x;
    const int blk   = blockIdx.x;
    const bool is_eq = (blk < 4096);
    const int w     = tid >> 6;
    const int lane  = tid & 63;
    const int col   = lane & 31;
    const int khalf = lane >> 5;
    const int ncol  = 32 * w + col;
    const int wofs  = ncol * 16 + khalf * 8;
    const bool even = (col & 1) == 0;
    // perm selectors for the pair-store exchange (per-lane constants):
    //  even lane: rows r0,r0+1   = (own.h0|nb.h0), (own.h1|nb.h1) from u.x
    //  odd  lane: rows r0+2,r0+3 = (nb.h2|own.h2), (nb.h3|own.h3) from u.y
    const uint32_t sel_lo = even ? 0x01000504u : 0x05040100u;
    const uint32_t sel_hi = even ? 0x03020706u : 0x07060302u;

    // ---- earliest VMEM: the point coordinates (oldest in queue) ----
    float tv, xv;
    if (is_eq) {
        const float2 t2 = ((const float2*)tx_eq)[blk * 32 + (tid >> 3)];
        tv = t2.x; xv = t2.y;
    } else {
        const int p  = tid >> 1;
        const int gp = (blk - 4096) * 128 + p;
        const float2* src = (gp < 4096) ? (const float2*)tx_init : (const float2*)tx_bnd;
        const int idx = (gp < 4096) ? gp : gp - 4096;
        const float2 t2 = src[idx];
        tv = t2.x; xv = t2.y;
    }

    // ---- layer-0 B prefetch: issued here, consumed after the input barrier ----
    const _Float16* ph = wt + wofs;
    half8 q0 = *(const half8*)(ph);
    half8 q1 = *(const half8*)(ph + 2048);
    half8 q2 = *(const half8*)(ph + 4096);
    half8 q3 = *(const half8*)(ph + 6144);
    half8 q4 = *(const half8*)(ph + 8192);
    half8 q5 = *(const half8*)(ph + 10240);
    half8 q6 = *(const half8*)(ph + 12288);
    half8 q7 = *(const half8*)(ph + 14336);

    // never-written zero C-operand (init once, reused all 3 layers)
    f32x16 Z;
    #pragma unroll
    for (int e = 0; e < 16; ++e) Z[e] = 0.f;

    // ---- input layer (K=2, pointwise, fp32) ----
    if (is_eq) {
        const int p  = tid >> 3;                 // 0..31
        const int f0 = (tid & 7) * 16;
        const int m0 = 4 * p;
        #pragma unroll
        for (int half = 0; half < 2; ++half) {
            const int fb = f0 + 8 * half;
            float vch[4][8];
            #pragma unroll
            for (int j = 0; j < 8; ++j) {
                const int f = fb + j;
                const float w0v = W0[f];             // dz/dt
                const float w1v = W0[128 + f];       // dz/dx
                const float z = fmaf(tv, w0v, fmaf(xv, w1v, b0[f]));
                const float a = fast_tanh(z);
                const float s = 1.f - a * a;
                vch[0][j] = a;
                vch[1][j] = s * w0v;
                vch[2][j] = s * w1v;
                vch[3][j] = -2.f * a * s * w1v * w1v;
            }
            #pragma unroll
            for (int c = 0; c < 4; ++c) {
                half8 hh;
                #pragma unroll
                for (int j = 0; j < 8; ++j) hh[j] = (_Float16)vch[c][j];
                *(half8*)&Hh[m0 + c][fb] = hh;
            }
        }
    } else {
        const int p  = tid >> 1;                 // 0..127 == row m
        const int f0 = (tid & 1) * 64;
        #pragma unroll
        for (int g = 0; g < 8; ++g) {
            half8 hh;
            #pragma unroll
            for (int j = 0; j < 8; ++j) {
                const int f = f0 + 8 * g + j;
                hh[j] = (_Float16)fast_tanh(fmaf(tv, W0[f], fmaf(xv, W0[128 + f], b0[f])));
            }
            *(half8*)&Hh[p][f0 + 8 * g] = hh;
        }
    }
    __syncthreads();

    const float* barr[3] = {b1, b2, b3};

    #pragma unroll 1
    for (int layer = 0; layer < 3; ++layer) {
        const float bias = barr[layer][ncol];

        f32x16 acc0, acc1, acc2, acc3;

#define KSTEP0(Q)                                                             \
        {                                                                     \
            const int k0 = khalf * 8;                                         \
            const half8 ah0 = *(const half8*)&Hh[col][k0];                    \
            const half8 ah1 = *(const half8*)&Hh[32 + col][k0];               \
            const half8 ah2 = *(const half8*)&Hh[64 + col][k0];               \
            const half8 ah3 = *(const half8*)&Hh[96 + col][k0];               \
            acc0 = __builtin_amdgcn_mfma_f32_32x32x16_f16(ah0, Q, Z, 0, 0, 0); \
            acc1 = __builtin_amdgcn_mfma_f32_32x32x16_f16(ah1, Q, Z, 0, 0, 0); \
            acc2 = __builtin_amdgcn_mfma_f32_32x32x16_f16(ah2, Q, Z, 0, 0, 0); \
            acc3 = __builtin_amdgcn_mfma_f32_32x32x16_f16(ah3, Q, Z, 0, 0, 0); \
        }
#define KSTEP(KT, Q)                                                          \
        {                                                                     \
            const int k0 = KT * 16 + khalf * 8;                               \
            const half8 ah0 = *(const half8*)&Hh[col][k0];                    \
            const half8 ah1 = *(const half8*)&Hh[32 + col][k0];               \
            const half8 ah2 = *(const half8*)&Hh[64 + col][k0];               \
            const half8 ah3 = *(const half8*)&Hh[96 + col][k0];               \
            acc0 = __builtin_amdgcn_mfma_f32_32x32x16_f16(ah0, Q, acc0, 0, 0, 0); \
            acc1 = __builtin_amdgcn_mfma_f32_32x32x16_f16(ah1, Q, acc1, 0, 0, 0); \
            acc2 = __builtin_amdgcn_mfma_f32_32x32x16_f16(ah2, Q, acc2, 0, 0, 0); \
            acc3 = __builtin_amdgcn_mfma_f32_32x32x16_f16(ah3, Q, acc3, 0, 0, 0); \
        }
        KSTEP0(q0) KSTEP(1, q1) KSTEP(2, q2) KSTEP(3, q3)
        KSTEP(4, q4) KSTEP(5, q5) KSTEP(6, q6) KSTEP(7, q7)
#undef KSTEP0
#undef KSTEP

        // ---- next layer's B prefetch: q-regs just consumed, reload now so
        // L2 latency hides under epilogue compute + both barriers.
        if (layer < 2) {
            ph += 16384;
            q0 = *(const half8*)(ph);
            q1 = *(const half8*)(ph + 2048);
            q2 = *(const half8*)(ph + 4096);
            q3 = *(const half8*)(ph + 6144);
            q4 = *(const half8*)(ph + 8192);
            q5 = *(const half8*)(ph + 10240);
            q6 = *(const half8*)(ph + 12288);
            q7 = *(const half8*)(ph + 14336);
        }

        // epilogue COMPUTE (registers only, before the barrier). C-layout:
        // reg group 4g..4g+3 = rows mt*32+8g+4khalf+{0..3} = the 4 derivative
        // channels of one point (eq) -> chain rule in registers. Then the
        // lane^1 pair-exchange packs (H[r][2j],H[r][2j+1]) words: even lane
        // keeps rows r0,r0+1; odd lane rows r0+2,r0+3.
        uint32_t wA[4][4], wB[4][4];
        #pragma unroll
        for (int mt = 0; mt < 4; ++mt)
            #pragma unroll
            for (int g = 0; g < 4; ++g) {
                const float A0 = (mt == 0 ? acc0 : mt == 1 ? acc1 : mt == 2 ? acc2 : acc3)[4 * g + 0];
                const float A1 = (mt == 0 ? acc0 : mt == 1 ? acc1 : mt == 2 ? acc2 : acc3)[4 * g + 1];
                const float A2 = (mt == 0 ? acc0 : mt == 1 ? acc1 : mt == 2 ? acc2 : acc3)[4 * g + 2];
                const float A3 = (mt == 0 ? acc0 : mt == 1 ? acc1 : mt == 2 ? acc2 : acc3)[4 * g + 3];
                half4 hv;
                if (is_eq) {
                    const float t = fast_tanh(A0 + bias);
                    const float s = 1.f - t * t;
                    hv[0] = (_Float16)t;
                    hv[1] = (_Float16)(s * A1);
                    hv[2] = (_Float16)(s * A2);
                    hv[3] = (_Float16)fmaf(s, A3, -2.f * t * s * A2 * A2);
                } else {
                    hv[0] = (_Float16)fast_tanh(A0 + bias);
                    hv[1] = (_Float16)fast_tanh(A1 + bias);
                    hv[2] = (_Float16)fast_tanh(A2 + bias);
                    hv[3] = (_Float16)fast_tanh(A3 + bias);
                }
                union { half4 h; uint32_t u[2]; } uu; uu.h = hv;
                // send: even lane offers u.y (its h2h3), odd offers u.x (its h0h1)
                const uint32_t send = even ? uu.u[1] : uu.u[0];
                const uint32_t recv = dpp_x1(send);
                const uint32_t own  = even ? uu.u[0] : uu.u[1];
                wA[mt][g] = __builtin_amdgcn_perm(own, recv, sel_lo);
                wB[mt][g] = __builtin_amdgcn_perm(own, recv, sel_hi);
            }

        __syncthreads();   // all reads of H done -> in-place overwrite safe

        // epilogue STORE (the only work between the two barriers): 32 b32
        {
            uint32_t* const hw = (uint32_t*)&Hh[0][0];
            const int cb = (32 * w + (col & ~1)) >> 1;      // word col
            const int rb = 4 * khalf + (even ? 0 : 2);      // row offset in group
            #pragma unroll
            for (int mt = 0; mt < 4; ++mt)
                #pragma unroll
                for (int g = 0; g < 4; ++g) {
                    const int r = mt * 32 + 8 * g + rb;
                    hw[r * (HS / 2) + cb]       = wA[mt][g];
                    hw[(r + 1) * (HS / 2) + cb] = wB[mt][g];
                }
        }
        __syncthreads();
    }

    // ---- final layer (128 -> 1): thread t reduces k-half (t&1) of row t>>1
    {
        const float b4v = b4[0];
        const int m = tid >> 1;
        const int q = tid & 1;
        float dot = 0.f;
        #pragma unroll
        for (int g = 0; g < 8; ++g) {
            const int f = 64 * q + 8 * g;
            const half8 hh = *(const half8*)&Hh[m][f];
            const float4 wa = *(const float4*)&W4[f];
            const float4 wb = *(const float4*)&W4[f + 4];
            dot = fmaf((float)hh[0], wa.x, dot);
            dot = fmaf((float)hh[1], wa.y, dot);
            dot = fmaf((float)hh[2], wa.z, dot);
            dot = fmaf((float)hh[3], wa.w, dot);
            dot = fmaf((float)hh[4], wb.x, dot);
            dot = fmaf((float)hh[5], wb.y, dot);
            dot = fmaf((float)hh[6], wb.z, dot);
            dot = fmaf((float)hh[7], wb.w, dot);
        }
        dot += __shfl_xor(dot, 1);   // full row-dot at both lanes of the pair

        if (is_eq) {
            // wave w holds rows [32w,32w+32) = points [8w,8w+8);
            // row r of point pl (=4pl+c) sits at lanes 8pl+2c (+q).
            const int base = (lane & 7) * 8;
            const float uu   = __shfl(dot, base + 0) + b4v;
            const float utv  = __shfl(dot, base + 2);
            const float uxv  = __shfl(dot, base + 4);
            const float uxxv = __shfl(dot, base + 6);
            if (lane < 8)
                out[blk * 32 + 8 * w + lane] = fmaf(uu, uxv, utv) - NU_F * uxxv;
        } else {
            if (q == 0)
                out[131072 + (blk - 4096) * 128 + m] = dot + b4v;
        }
    }
}

extern "C" void kernel_launch(void* const* d_in, const int* in_sizes, int n_in,
                              void* d_out, int out_size, void* d_ws, size_t ws_size,
                              hipStream_t stream)
{
    const float* tx_eq   = (const float*)d_in[0];
    const float* tx_init = (const float*)d_in[1];
    const float* tx_bnd  = (const float*)d_in[2];
    const float* W0 = (const float*)d_in[3];
    const float* b0 = (const float*)d_in[4];
    const float* W1 = (const float*)d_in[5];
    const float* b1 = (const float*)d_in[6];
    const float* W2 = (const float*)d_in[7];
    const float* b2 = (const float*)d_in[8];
    const float* W3 = (const float*)d_in[9];
    const float* b3 = (const float*)d_in[10];
    const float* W4 = (const float*)d_in[11];
    const float* b4 = (const float*)d_in[12];
    float* out = (float*)d_out;
    _Float16* wt = (_Float16*)d_ws;   // needs 98304 B

    hipLaunchKernelGGL(prep_kernel, dim3(192), dim3(256), 0, stream, W1, W2, W3, wt);
    // 4096 eq blocks (32 pts) + 64 ib blocks (128 pts)
    hipLaunchKernelGGL(pinn_kernel, dim3(4160), dim3(256), 0, stream,
                       tx_eq, tx_init, tx_bnd, W0, b0, b1, b2, b3, W4, b4,
                       (const _Float16*)wt, out);
}

// Round 8
// 160.737 us; speedup vs baseline: 2.2058x; 1.0224x over previous
//
#include <hip/hip_runtime.h>
#include <math.h>

#define NU_F 0.0031830988618379067f
#define HS 136   // halves per H row: 17*8 -> 16B-aligned, odd 16B-stride = bank-balanced
#define TANH_C 2.8853900817779268f   // 2/ln(2): tanh(x) = 1 - 2/(2^(Cx)+1)

typedef __attribute__((ext_vector_type(8))) _Float16 half8;
typedef __attribute__((ext_vector_type(4))) _Float16 half4;
typedef __attribute__((ext_vector_type(16))) float f32x16;

// tanh via exp2 + fast rcp: ~5 VALU (2 on trans pipe). inf-safe: e=inf -> 1, e=0 -> -1.
__device__ __forceinline__ float fast_tanh(float x) {
    const float e = __builtin_amdgcn_exp2f(x * TANH_C);  // e^(2x)
    const float r = __builtin_amdgcn_rcpf(e + 1.f);
    return fmaf(-2.f, r, 1.f);
}

// tanh(x + b) with b pre-scaled by TANH_C: one fma instead of add+mul.
__device__ __forceinline__ float fast_tanh_pre(float x, float b2) {
    const float e = __builtin_amdgcn_exp2f(fmaf(x, TANH_C, b2));
    const float r = __builtin_amdgcn_rcpf(e + 1.f);
    return fmaf(-2.f, r, 1.f);
}

// ---------------------------------------------------------------------------
// Weight prep: W[l][k][n] fp32 -> k-tiled fp16:
//   idx = l*16384 + (k>>4)*2048 + n*16 + (k&15)
// A wave's per-kt B-read (16 halves/lane, n-contiguous) is one 1KB block.
// ---------------------------------------------------------------------------
__global__ void prep_kernel(const float* __restrict__ W1,
                            const float* __restrict__ W2,
                            const float* __restrict__ W3,
                            _Float16* __restrict__ ws)
{
    const int g = blockIdx.x * 256 + threadIdx.x;   // 0..49151
    const int l = g >> 14;
    const int r = g & 16383;
    const int n = r & 127;
    const int k = r >> 7;
    const float* W = (l == 0) ? W1 : (l == 1) ? W2 : W3;
    const float w = W[k * 128 + n];
    ws[l * 16384 + (k >> 4) * 2048 + n * 16 + (k & 15)] = (_Float16)w;
}

// ---------------------------------------------------------------------------
// R3 structure (proven best: M=128, 1x4 N-split, Z-trick, B software-
// pipeline, 4 blk/CU; 60 VGPR + 64 AGPR = 124 <= 128 -> layout-optimal at
// the 4-waves/SIMD register tier) + this round:
//   - s_setprio(1) around the 32-MFMA cluster (T5): 4 independent staggered
//     blocks/CU = the attn-like regime where issue-priority pays.
//   - bias folded into the exp2 argument (add eliminated).
//   - u_xx chain product re-associated to reuse s*A2 / s*w1 (1 mul saved).
// Blocks 0..4095: equation, 32 pts (M=128 rows, m = 4p + channel).
// Blocks 4096..4159: init/bound forward-only, 128 pts (m = p).
// Wave w computes cols [32w,32w+32) for all 128 rows (mt=0..3).
// ---------------------------------------------------------------------------
__launch_bounds__(256, 4)
__global__ void pinn_kernel(const float* __restrict__ tx_eq,
                            const float* __restrict__ tx_init,
                            const float* __restrict__ tx_bnd,
                            const float* __restrict__ W0, const float* __restrict__ b0,
                            const float* __restrict__ b1, const float* __restrict__ b2,
                            const float* __restrict__ b3,
                            const float* __restrict__ W4, const float* __restrict__ b4,
                            const _Float16* __restrict__ wt,
                            float* __restrict__ out)
{
    __shared__ _Float16 Hh[128][HS];   // 34.8 KB, in-place across layers

    const int tid   = threadIdx.x;
    const int blk   = blockIdx.x;
    const bool is_eq = (blk < 4096);
    const int w     = tid >> 6;
    const int lane  = tid & 63;
    const int col   = lane & 31;
    const int khalf = lane >> 5;
    const int ncol  = 32 * w + col;
    const int wofs  = ncol * 16 + khalf * 8;

    // ---- earliest VMEM: the point coordinates (oldest in queue) ----
    float tv, xv;
    if (is_eq) {
        const float2 t2 = ((const float2*)tx_eq)[blk * 32 + (tid >> 3)];
        tv = t2.x; xv = t2.y;
    } else {
        const int p  = tid >> 1;
        const int gp = (blk - 4096) * 128 + p;
        const float2* src = (gp < 4096) ? (const float2*)tx_init : (const float2*)tx_bnd;
        const int idx = (gp < 4096) ? gp : gp - 4096;
        const float2 t2 = src[idx];
        tv = t2.x; xv = t2.y;
    }

    // ---- layer-0 B prefetch: issued here, consumed after the input barrier ----
    const _Float16* ph = wt + wofs;
    half8 q0 = *(const half8*)(ph);
    half8 q1 = *(const half8*)(ph + 2048);
    half8 q2 = *(const half8*)(ph + 4096);
    half8 q3 = *(const half8*)(ph + 6144);
    half8 q4 = *(const half8*)(ph + 8192);
    half8 q5 = *(const half8*)(ph + 10240);
    half8 q6 = *(const half8*)(ph + 12288);
    half8 q7 = *(const half8*)(ph + 14336);

    // never-written zero C-operand (init once, reused all 3 layers)
    f32x16 Z;
    #pragma unroll
    for (int e = 0; e < 16; ++e) Z[e] = 0.f;

    // ---- input layer (K=2, pointwise, fp32) ----
    if (is_eq) {
        const int p  = tid >> 3;                 // 0..31
        const int f0 = (tid & 7) * 16;
        const int m0 = 4 * p;
        #pragma unroll
        for (int half = 0; half < 2; ++half) {
            const int fb = f0 + 8 * half;
            float vch[4][8];
            #pragma unroll
            for (int j = 0; j < 8; ++j) {
                const int f = fb + j;
                const float w0v = W0[f];             // dz/dt
                const float w1v = W0[128 + f];       // dz/dx
                const float z = fmaf(tv, w0v, fmaf(xv, w1v, b0[f]));
                const float a = fast_tanh(z);
                const float s = 1.f - a * a;
                const float v2 = s * w1v;
                vch[0][j] = a;
                vch[1][j] = s * w0v;
                vch[2][j] = v2;
                vch[3][j] = ((a * v2) * w1v) * -2.f;
            }
            #pragma unroll
            for (int c = 0; c < 4; ++c) {
                half8 hh;
                #pragma unroll
                for (int j = 0; j < 8; ++j) hh[j] = (_Float16)vch[c][j];
                *(half8*)&Hh[m0 + c][fb] = hh;
            }
        }
    } else {
        const int p  = tid >> 1;                 // 0..127 == row m
        const int f0 = (tid & 1) * 64;
        #pragma unroll
        for (int g = 0; g < 8; ++g) {
            half8 hh;
            #pragma unroll
            for (int j = 0; j < 8; ++j) {
                const int f = f0 + 8 * g + j;
                hh[j] = (_Float16)fast_tanh(fmaf(tv, W0[f], fmaf(xv, W0[128 + f], b0[f])));
            }
            *(half8*)&Hh[p][f0 + 8 * g] = hh;
        }
    }
    __syncthreads();

    const float* barr[3] = {b1, b2, b3};

    #pragma unroll 1
    for (int layer = 0; layer < 3; ++layer) {
        const float bias2 = barr[layer][ncol] * TANH_C;

        f32x16 acc0, acc1, acc2, acc3;

#define KSTEP0(Q)                                                             \
        {                                                                     \
            const int k0 = khalf * 8;                                         \
            const half8 ah0 = *(const half8*)&Hh[col][k0];                    \
            const half8 ah1 = *(const half8*)&Hh[32 + col][k0];               \
            const half8 ah2 = *(const half8*)&Hh[64 + col][k0];               \
            const half8 ah3 = *(const half8*)&Hh[96 + col][k0];               \
            acc0 = __builtin_amdgcn_mfma_f32_32x32x16_f16(ah0, Q, Z, 0, 0, 0); \
            acc1 = __builtin_amdgcn_mfma_f32_32x32x16_f16(ah1, Q, Z, 0, 0, 0); \
            acc2 = __builtin_amdgcn_mfma_f32_32x32x16_f16(ah2, Q, Z, 0, 0, 0); \
            acc3 = __builtin_amdgcn_mfma_f32_32x32x16_f16(ah3, Q, Z, 0, 0, 0); \
        }
#define KSTEP(KT, Q)                                                          \
        {                                                                     \
            const int k0 = KT * 16 + khalf * 8;                               \
            const half8 ah0 = *(const half8*)&Hh[col][k0];                    \
            const half8 ah1 = *(const half8*)&Hh[32 + col][k0];               \
            const half8 ah2 = *(const half8*)&Hh[64 + col][k0];               \
            const half8 ah3 = *(const half8*)&Hh[96 + col][k0];               \
            acc0 = __builtin_amdgcn_mfma_f32_32x32x16_f16(ah0, Q, acc0, 0, 0, 0); \
            acc1 = __builtin_amdgcn_mfma_f32_32x32x16_f16(ah1, Q, acc1, 0, 0, 0); \
            acc2 = __builtin_amdgcn_mfma_f32_32x32x16_f16(ah2, Q, acc2, 0, 0, 0); \
            acc3 = __builtin_amdgcn_mfma_f32_32x32x16_f16(ah3, Q, acc3, 0, 0, 0); \
        }
        __builtin_amdgcn_s_setprio(1);
        KSTEP0(q0) KSTEP(1, q1) KSTEP(2, q2) KSTEP(3, q3)
        KSTEP(4, q4) KSTEP(5, q5) KSTEP(6, q6) KSTEP(7, q7)
        __builtin_amdgcn_s_setprio(0);
#undef KSTEP0
#undef KSTEP

        // ---- next layer's B prefetch: q-regs just consumed, reload now so
        // L2 latency hides under epilogue compute + both barriers.
        if (layer < 2) {
            ph += 16384;
            q0 = *(const half8*)(ph);
            q1 = *(const half8*)(ph + 2048);
            q2 = *(const half8*)(ph + 4096);
            q3 = *(const half8*)(ph + 6144);
            q4 = *(const half8*)(ph + 8192);
            q5 = *(const half8*)(ph + 10240);
            q6 = *(const half8*)(ph + 12288);
            q7 = *(const half8*)(ph + 14336);
        }

        // epilogue COMPUTE (registers only, before the barrier). C-layout:
        // reg group 4g..4g+3 = rows mt*32+8g+4khalf+{0..3} = the 4 derivative
        // channels of one point (eq) -> chain rule in registers.
        half4 h16[4][4];
        #pragma unroll
        for (int mt = 0; mt < 4; ++mt)
            #pragma unroll
            for (int g = 0; g < 4; ++g) {
                const float A0 = (mt == 0 ? acc0 : mt == 1 ? acc1 : mt == 2 ? acc2 : acc3)[4 * g + 0];
                const float A1 = (mt == 0 ? acc0 : mt == 1 ? acc1 : mt == 2 ? acc2 : acc3)[4 * g + 1];
                const float A2 = (mt == 0 ? acc0 : mt == 1 ? acc1 : mt == 2 ? acc2 : acc3)[4 * g + 2];
                const float A3 = (mt == 0 ? acc0 : mt == 1 ? acc1 : mt == 2 ? acc2 : acc3)[4 * g + 3];
                half4 hv;
                if (is_eq) {
                    const float t = fast_tanh_pre(A0, bias2);
                    const float s = 1.f - t * t;
                    const float sA2 = s * A2;
                    hv[0] = (_Float16)t;
                    hv[1] = (_Float16)(s * A1);
                    hv[2] = (_Float16)sA2;
                    hv[3] = (_Float16)fmaf(s, A3, -2.f * ((t * sA2) * A2));
                } else {
                    hv[0] = (_Float16)fast_tanh_pre(A0, bias2);
                    hv[1] = (_Float16)fast_tanh_pre(A1, bias2);
                    hv[2] = (_Float16)fast_tanh_pre(A2, bias2);
                    hv[3] = (_Float16)fast_tanh_pre(A3, bias2);
                }
                h16[mt][g] = hv;
            }

        __syncthreads();   // all reads of H done -> in-place overwrite safe

        // epilogue STORE (the only work between the two barriers)
        #pragma unroll
        for (int mt = 0; mt < 4; ++mt)
            #pragma unroll
            for (int g = 0; g < 4; ++g) {
                const int mrow0 = mt * 32 + 8 * g + 4 * khalf;
                Hh[mrow0 + 0][ncol] = h16[mt][g][0];
                Hh[mrow0 + 1][ncol] = h16[mt][g][1];
                Hh[mrow0 + 2][ncol] = h16[mt][g][2];
                Hh[mrow0 + 3][ncol] = h16[mt][g][3];
            }
        __syncthreads();
    }

    // ---- final layer (128 -> 1): thread t reduces k-half (t&1) of row t>>1
    {
        const float b4v = b4[0];
        const int m = tid >> 1;
        const int q = tid & 1;
        float dot = 0.f;
        #pragma unroll
        for (int g = 0; g < 8; ++g) {
            const int f = 64 * q + 8 * g;
            const half8 hh = *(const half8*)&Hh[m][f];
            const float4 wa = *(const float4*)&W4[f];
            const float4 wb = *(const float4*)&W4[f + 4];
            dot = fmaf((float)hh[0], wa.x, dot);
            dot = fmaf((float)hh[1], wa.y, dot);
            dot = fmaf((float)hh[2], wa.z, dot);
            dot = fmaf((float)hh[3], wa.w, dot);
            dot = fmaf((float)hh[4], wb.x, dot);
            dot = fmaf((float)hh[5], wb.y, dot);
            dot = fmaf((float)hh[6], wb.z, dot);
            dot = fmaf((float)hh[7], wb.w, dot);
        }
        dot += __shfl_xor(dot, 1);   // full row-dot at both lanes of the pair

        if (is_eq) {
            // wave w holds rows [32w,32w+32) = points [8w,8w+8);
            // row r of point pl (=4pl+c) sits at lanes 8pl+2c (+q).
            const int base = (lane & 7) * 8;
            const float uu   = __shfl(dot, base + 0) + b4v;
            const float utv  = __shfl(dot, base + 2);
            const float uxv  = __shfl(dot, base + 4);
            const float uxxv = __shfl(dot, base + 6);
            if (lane < 8)
                out[blk * 32 + 8 * w + lane] = fmaf(uu, uxv, utv) - NU_F * uxxv;
        } else {
            if (q == 0)
                out[131072 + (blk - 4096) * 128 + m] = dot + b4v;
        }
    }
}

extern "C" void kernel_launch(void* const* d_in, const int* in_sizes, int n_in,
                              void* d_out, int out_size, void* d_ws, size_t ws_size,
                              hipStream_t stream)
{
    const float* tx_eq   = (const float*)d_in[0];
    const float* tx_init = (const float*)d_in[1];
    const float* tx_bnd  = (const float*)d_in[2];
    const float* W0 = (const float*)d_in[3];
    const float* b0 = (const float*)d_in[4];
    const float* W1 = (const float*)d_in[5];
    const float* b1 = (const float*)d_in[6];
    const float* W2 = (const float*)d_in[7];
    const float* b2 = (const float*)d_in[8];
    const float* W3 = (const float*)d_in[9];
    const float* b3 = (const float*)d_in[10];
    const float* W4 = (const float*)d_in[11];
    const float* b4 = (const float*)d_in[12];
    float* out = (float*)d_out;
    _Float16* wt = (_Float16*)d_ws;   // needs 98304 B

    hipLaunchKernelGGL(prep_kernel, dim3(192), dim3(256), 0, stream, W1, W2, W3, wt);
    // 4096 eq blocks (32 pts) + 64 ib blocks (128 pts)
    hipLaunchKernelGGL(pinn_kernel, dim3(4160), dim3(256), 0, stream,
                       tx_eq, tx_init, tx_bnd, W0, b0, b1, b2, b3, W4, b4,
                       (const _Float16*)wt, out);
}